// Round 1
// baseline (5117.729 us; speedup 1.0000x reference)
//
#include <hip/hip_runtime.h>
#include <math.h>

// Problem constants
#define NTT 64
#define NQQ 256
#define NN  16384      // NT*NQ
#define EE  262144     // edges per scale
#define FF  160

// Workspace layout (float offsets)
#define R_OFF    0          // 64*9
#define TR_OFF   576        // 64*3
#define QE_OFF   768        // 64*128
#define G_OFF    8960       // 2*64*64
#define QX_OFF   17152      // 16384*3
#define QF_OFF   66304      // 16384*160
#define N0_OFF   2687744    // 16384*160
#define N1_OFF   5309184    // 16384*160
#define C0_OFF   7930624    // 16384
#define C1_OFF   7947008    // 16384
#define WS_END   7963392

// ---------------------------------------------------------------------------
// Kernel 1: rotation matrices + translation + time embedding qemb = te@W_qt+b
// ---------------------------------------------------------------------------
__global__ __launch_bounds__(128) void prep_rt_qemb(
    const float* __restrict__ Ts, const float* __restrict__ timev,
    const float* __restrict__ W_qt, const float* __restrict__ b_qt,
    float* __restrict__ ws)
{
  int t = blockIdx.x, j = threadIdx.x;
  __shared__ float te[128];
  float tt = timev[t];
  int h = j & 63;
  float fr = __expf(-logf(10000.f) * (float)h / 63.f);
  float a = tt * fr;
  te[j] = (j < 64) ? sinf(a) : cosf(a);
  if (j == 0) {
    float qw = Ts[t*7+0], qx = Ts[t*7+1], qy = Ts[t*7+2], qz = Ts[t*7+3];
    float nrm = sqrtf(qw*qw + qx*qx + qy*qy + qz*qz);
    qw /= nrm; qx /= nrm; qy /= nrm; qz /= nrm;
    float* R = ws + R_OFF + t*9;
    R[0] = 1.f - 2.f*(qy*qy + qz*qz); R[1] = 2.f*(qx*qy - qw*qz); R[2] = 2.f*(qx*qz + qw*qy);
    R[3] = 2.f*(qx*qy + qw*qz); R[4] = 1.f - 2.f*(qx*qx + qz*qz); R[5] = 2.f*(qy*qz - qw*qx);
    R[6] = 2.f*(qx*qz - qw*qy); R[7] = 2.f*(qy*qz + qw*qx); R[8] = 1.f - 2.f*(qx*qx + qy*qy);
    ws[TR_OFF + t*3 + 0] = Ts[t*7+4];
    ws[TR_OFF + t*3 + 1] = Ts[t*7+5];
    ws[TR_OFF + t*3 + 2] = Ts[t*7+6];
  }
  __syncthreads();
  float acc = b_qt[j];
  for (int k = 0; k < 128; k++) acc += te[k] * W_qt[k*128 + j];
  ws[QE_OFF + t*128 + j] = acc;
}

// ---------------------------------------------------------------------------
// Kernel 2: G[s][t][o] = b1[s][o] + sum_k qemb[t][k] * W1[s][8+k][o]
// ---------------------------------------------------------------------------
__global__ __launch_bounds__(64) void prep_G(
    const float* __restrict__ W1_r, const float* __restrict__ b1_r,
    float* __restrict__ ws)
{
  int t = blockIdx.x, sidx = blockIdx.y, o = threadIdx.x;
  const float* W1 = W1_r + sidx*136*64;
  const float* qe = ws + QE_OFF + t*128;
  float acc = b1_r[sidx*64 + o];
  for (int k = 0; k < 128; k++) acc += qe[k] * W1[(8+k)*64 + o];
  ws[G_OFF + sidx*4096 + t*64 + o] = acc;
}

// ---------------------------------------------------------------------------
// Kernel 3: qx_flat (transformed query positions) + qf_t (transformed feats)
// ---------------------------------------------------------------------------
__global__ __launch_bounds__(256) void prep_Q(
    const float* __restrict__ query_x, const float* __restrict__ query_f,
    float* __restrict__ ws)
{
  int t = blockIdx.x, tid = threadIdx.x;
  __shared__ float Rs[9], tr[3];
  if (tid < 9) Rs[tid] = ws[R_OFF + t*9 + tid];
  if (tid < 3) tr[tid] = ws[TR_OFF + t*3 + tid];
  __syncthreads();
  for (int el = tid; el < 768; el += 256) {
    int q = el / 3, i = el - q*3;
    const float* x = query_x + q*3;
    ws[QX_OFF + t*768 + el] = Rs[i*3+0]*x[0] + Rs[i*3+1]*x[1] + Rs[i*3+2]*x[2] + tr[i];
  }
  for (int el = tid; el < 40960; el += 256) {
    int q = el / 160, j = el - q*160;
    float v;
    if (j < 64) {
      v = query_f[q*160 + j];
    } else {
      int c = (j - 64) / 3, i = (j - 64) - c*3;
      const float* qv = query_f + q*160 + 64 + c*3;
      v = Rs[i*3+0]*qv[0] + Rs[i*3+1]*qv[1] + Rs[i*3+2]*qv[2];
    }
    ws[QF_OFF + (size_t)t*40960 + el] = v;
  }
}

// ---------------------------------------------------------------------------
// Kernel 4: per-edge MLP + message + atomic segment accumulate (one scale)
// lane-per-edge; weights via wave-uniform scalar loads; acc[192] in VGPRs
// ---------------------------------------------------------------------------
__global__ __launch_bounds__(256, 2) void edge_kernel(
    const float* __restrict__ key_x, const float* __restrict__ key_f,
    const int* __restrict__ esrc, const int* __restrict__ edst,
    const float* __restrict__ W1, const float* __restrict__ W2,
    const float* __restrict__ b2, const float* __restrict__ Gtab,
    const float* __restrict__ qx_flat,
    float* __restrict__ num, float* __restrict__ cnt)
{
  __shared__ float Gs[64*65];   // stride 65: random-t gathers spread banks
  for (int idx = threadIdx.x; idx < 4096; idx += 256)
    Gs[(idx >> 6)*65 + (idx & 63)] = Gtab[idx];
  __syncthreads();

  int e = blockIdx.x*256 + threadIdx.x;
  int s = esrc[e], d = edst[e];
  const float* qx = qx_flat + d*3;
  float rel0 = key_x[s*3+0] - qx[0];
  float rel1 = key_x[s*3+1] - qx[1];
  float rel2 = key_x[s*3+2] - qx[2];
  float r = sqrtf(rel0*rel0 + rel1*rel1 + rel2*rel2);
  float rinv = 1.f / (r + 1e-8f);
  float dir0 = rel0*rinv, dir1 = rel1*rinv, dir2 = rel2*rinv;
  float rb[8];
  #pragma unroll
  for (int j = 0; j < 8; j++) {
    float dd = r - (float)j * (4.f/7.f);
    rb[j] = __expf(-4.f * dd * dd);
  }
  int t = d >> 8;
  const float* grow = Gs + t*65;

  float acc[192];
  #pragma unroll
  for (int o = 0; o < 192; o++) acc[o] = b2[o];

  #pragma unroll 1
  for (int kb = 0; kb < 8; kb++) {
    // just-in-time layer1 for this k-block (keeps h1 indices compile-time)
    float hb[8];
    #pragma unroll
    for (int ki = 0; ki < 8; ki++) {
      int kk = kb*8 + ki;
      float a = grow[kk];
      #pragma unroll
      for (int j = 0; j < 8; j++) a += rb[j] * W1[j*64 + kk];
      hb[ki] = a / (1.f + __expf(-a));   // silu
    }
    const float* w2k = W2 + kb*1536;
    #pragma unroll
    for (int ki = 0; ki < 8; ki++) {
      float hv = hb[ki];
      #pragma unroll
      for (int o = 0; o < 192; o++) acc[o] += hv * w2k[ki*192 + o];
    }
  }

  // message emit + atomic segment-sum
  atomicAdd(cnt + d, 1.f);
  const float* kf = key_f + (size_t)s * 160;
  float* nrow = num + (size_t)d * 160;

  #pragma unroll
  for (int c4 = 0; c4 < 32; c4 += 4) {
    const float4 ks4 = *(const float4*)(kf + c4);
    const float4 va  = *(const float4*)(kf + 64 + 3*c4);
    const float4 vb4 = *(const float4*)(kf + 64 + 3*c4 + 4);
    const float4 vc  = *(const float4*)(kf + 64 + 3*c4 + 8);
    float ksv[4] = {ks4.x, ks4.y, ks4.z, ks4.w};
    float kvv[4][3] = {{va.x, va.y, va.z}, {va.w, vb4.x, vb4.y},
                       {vb4.z, vb4.w, vc.x}, {vc.y, vc.z, vc.w}};
    #pragma unroll
    for (int u = 0; u < 4; u++) {
      int c = c4 + u;
      float k0 = kvv[u][0], k1 = kvv[u][1], k2 = kvv[u][2], ks = ksv[u];
      float dt = k0*dir0 + k1*dir1 + k2*dir2;
      atomicAdd(nrow + c, acc[c]*ks + acc[128+c]*dt);
      float cr0 = k1*dir2 - k2*dir1;
      float cr1 = k2*dir0 - k0*dir2;
      float cr2 = k0*dir1 - k1*dir0;
      float wvs_ = acc[64+c];
      float wsv_ = acc[96+c] * ks;
      float wvvv_ = acc[160+c];
      atomicAdd(nrow + 64 + 3*c + 0, wvs_*k0 + wsv_*dir0 + wvvv_*cr0);
      atomicAdd(nrow + 64 + 3*c + 1, wvs_*k1 + wsv_*dir1 + wvvv_*cr1);
      atomicAdd(nrow + 64 + 3*c + 2, wvs_*k2 + wsv_*dir2 + wvvv_*cr2);
    }
  }
  #pragma unroll
  for (int c4 = 32; c4 < 64; c4 += 4) {
    const float4 ks4 = *(const float4*)(kf + c4);
    atomicAdd(nrow + c4 + 0, acc[c4+0]*ks4.x);
    atomicAdd(nrow + c4 + 1, acc[c4+1]*ks4.y);
    atomicAdd(nrow + c4 + 2, acc[c4+2]*ks4.z);
    atomicAdd(nrow + c4 + 3, acc[c4+3]*ks4.w);
  }
}

// ---------------------------------------------------------------------------
// Kernel 5: tp_head (both heads in one wave) + rotation + final reductions
// lanes 0..31 -> head 0 (lin), lanes 32..63 -> head 1 (ang)
// ---------------------------------------------------------------------------
__global__ __launch_bounds__(64) void head_kernel(
    const float* __restrict__ num0, const float* __restrict__ num1,
    const float* __restrict__ cnt0, const float* __restrict__ cnt1,
    const float* __restrict__ qf_t, const float* __restrict__ Rtab,
    const float* __restrict__ query_x, const float* __restrict__ query_w,
    const float* __restrict__ p00, const float* __restrict__ prest,
    const float* __restrict__ Ws_tp, const float* __restrict__ Wv_tp,
    float* __restrict__ out)
{
  int n = blockIdx.x;
  int lane = threadIdx.x;
  int t = n >> 8, q = n & 255;
  __shared__ float sb[96];
  __shared__ float vb[96][3];
  const float* n0 = num0 + (size_t)n*160;
  const float* n1 = num1 + (size_t)n*160;
  const float* qf = qf_t + (size_t)n*160;
  float ic0 = 1.f / (cnt0[n] + 1e-8f);
  float ic1 = 1.f / (cnt1[n] + 1e-8f);
  int c = lane;
  if (c < 64) sb[c] = (n0[c]*ic0 + n1[c]*ic1) * qf[c];
  if (c < 32) {
    float ks = n0[c]*ic0 + n1[c]*ic1;
    float qs = qf[c];
    float k0 = n0[64+3*c+0]*ic0 + n1[64+3*c+0]*ic1;
    float k1 = n0[64+3*c+1]*ic0 + n1[64+3*c+1]*ic1;
    float k2 = n0[64+3*c+2]*ic0 + n1[64+3*c+2]*ic1;
    float q0 = qf[64+3*c+0], q1 = qf[64+3*c+1], q2 = qf[64+3*c+2];
    sb[64+c] = k0*q0 + k1*q1 + k2*q2;
    vb[c][0] = k0*qs;  vb[c][1] = k1*qs;  vb[c][2] = k2*qs;
    vb[32+c][0] = ks*q0;  vb[32+c][1] = ks*q1;  vb[32+c][2] = ks*q2;
    vb[64+c][0] = k1*q2 - k2*q1;
    vb[64+c][1] = k2*q0 - k0*q2;
    vb[64+c][2] = k0*q1 - k1*q0;
  }
  __syncthreads();

  int i = lane >> 5, o = lane & 31;
  const float* Ws = Ws_tp + i*96*33;
  const float* Wv = Wv_tp + i*96*32;
  const float* pp = p00 + i*64;
  const float* pr = prest + i*128;
  float g = 0.f, v0 = 0.f, v1 = 0.f, v2 = 0.f;
  for (int c2 = 0; c2 < 96; c2++) {
    float ps = (c2 < 64) ? pp[c2] : pr[c2];        // p00[i][c] / prest[i][2][c-64]
    float pv = (c2 < 64) ? pr[c2] : pr[c2 + 32];   // prest[i][0/1/3][...]
    g += sb[c2] * ps * Ws[c2*33 + o + 1];
    float pw = pv * Wv[c2*32 + o];
    v0 += vb[c2][0] * pw;
    v1 += vb[c2][1] * pw;
    v2 += vb[c2][2] * pw;
  }
  g = 1.f / (1.f + __expf(-g));
  v0 *= g; v1 *= g; v2 *= g;
  #pragma unroll
  for (int m = 16; m >= 1; m >>= 1) {
    v0 += __shfl_xor(v0, m, 32);
    v1 += __shfl_xor(v1, m, 32);
    v2 += __shfl_xor(v2, m, 32);
  }
  if (o == 0) {
    v0 *= (1.f/32.f); v1 *= (1.f/32.f); v2 *= (1.f/32.f);
    const float* R = Rtab + t*9;
    // R^T rotation (einsum 'tji,tqj->tqi')
    float r0 = R[0]*v0 + R[3]*v1 + R[6]*v2;
    float r1 = R[1]*v0 + R[4]*v1 + R[7]*v2;
    float r2 = R[2]*v0 + R[5]*v1 + R[8]*v2;
    float w = query_w[q];
    if (i == 0) {
      // lin head: lin_vel += w*lin ; ang_vel += w*cross(query_x, lin)
      atomicAdd(out + 192 + t*3 + 0, w*r0);
      atomicAdd(out + 192 + t*3 + 1, w*r1);
      atomicAdd(out + 192 + t*3 + 2, w*r2);
      float x0 = query_x[q*3+0], x1 = query_x[q*3+1], x2 = query_x[q*3+2];
      atomicAdd(out + t*3 + 0, w*(x1*r2 - x2*r1));
      atomicAdd(out + t*3 + 1, w*(x2*r0 - x0*r2));
      atomicAdd(out + t*3 + 2, w*(x0*r1 - x1*r0));
    } else {
      // ang head: ang_vel += w*ang
      atomicAdd(out + t*3 + 0, w*r0);
      atomicAdd(out + t*3 + 1, w*r1);
      atomicAdd(out + t*3 + 2, w*r2);
    }
  }
}

// ---------------------------------------------------------------------------
extern "C" void kernel_launch(void* const* d_in, const int* in_sizes, int n_in,
                              void* d_out, int out_size, void* d_ws, size_t ws_size,
                              hipStream_t stream)
{
  const float* Ts      = (const float*)d_in[0];
  const float* timev   = (const float*)d_in[1];
  const float* query_x = (const float*)d_in[2];
  const float* query_f = (const float*)d_in[3];
  const float* query_w = (const float*)d_in[4];
  const float* key_x_0 = (const float*)d_in[5];
  const float* key_f_0 = (const float*)d_in[6];
  const float* key_x_1 = (const float*)d_in[7];
  const float* key_f_1 = (const float*)d_in[8];
  const int*   es0     = (const int*)d_in[9];
  const int*   ed0     = (const int*)d_in[10];
  const int*   es1     = (const int*)d_in[11];
  const int*   ed1     = (const int*)d_in[12];
  const float* W_qt    = (const float*)d_in[13];
  const float* b_qt    = (const float*)d_in[14];
  const float* W1_r    = (const float*)d_in[15];
  const float* b1_r    = (const float*)d_in[16];
  const float* W2_r    = (const float*)d_in[17];
  const float* b2_r    = (const float*)d_in[18];
  const float* p00     = (const float*)d_in[19];
  const float* prest   = (const float*)d_in[20];
  const float* Ws_tp   = (const float*)d_in[21];
  const float* Wv_tp   = (const float*)d_in[22];
  float* ws  = (float*)d_ws;
  float* out = (float*)d_out;

  hipMemsetAsync(ws + N0_OFF, 0, (size_t)(WS_END - N0_OFF) * sizeof(float), stream);
  hipMemsetAsync(out, 0, 384 * sizeof(float), stream);

  prep_rt_qemb<<<64, 128, 0, stream>>>(Ts, timev, W_qt, b_qt, ws);
  prep_G<<<dim3(64, 2), 64, 0, stream>>>(W1_r, b1_r, ws);
  prep_Q<<<64, 256, 0, stream>>>(query_x, query_f, ws);

  edge_kernel<<<1024, 256, 0, stream>>>(
      key_x_0, key_f_0, es0, ed0,
      W1_r, W2_r, b2_r,
      ws + G_OFF, ws + QX_OFF,
      ws + N0_OFF, ws + C0_OFF);
  edge_kernel<<<1024, 256, 0, stream>>>(
      key_x_1, key_f_1, es1, ed1,
      W1_r + 136*64, W2_r + 64*192, b2_r + 192,
      ws + G_OFF + 4096, ws + QX_OFF,
      ws + N1_OFF, ws + C1_OFF);

  head_kernel<<<16384, 64, 0, stream>>>(
      ws + N0_OFF, ws + N1_OFF, ws + C0_OFF, ws + C1_OFF,
      ws + QF_OFF, ws + R_OFF,
      query_x, query_w, p00, prest, Ws_tp, Wv_tp, out);
}

// Round 2
// 845.297 us; speedup vs baseline: 6.0544x; 6.0544x over previous
//
#include <hip/hip_runtime.h>
#include <math.h>

// Problem constants
#define NTT 64
#define NQQ 256
#define NN  16384      // NT*NQ
#define EE  262144     // edges per scale

// Workspace layout (float offsets)
#define R_OFF     0          // 64*9
#define TR_OFF    576        // 64*3
#define QE_OFF    768        // 64*128
#define G_OFF     8960       // 2*64*64
#define QX_OFF    17152      // 16384*3
#define QF_OFF    66304      // 16384*160
#define N0_OFF    2687744    // 16384*160
#define N1_OFF    5309184    // 16384*160
#define HIST_OFF  7930624    // 2*16384 (int)
#define START_OFF 7963392    // 2*16384 (int)
#define FILL_OFF  7996160    // 2*16384 (int)
#define SSRC_OFF  8028928    // 2*262144 (int)
#define SDST_OFF  8553216    // 2*262144 (int)
#define W2T_OFF   9077504    // 2*192*64
#define PART_OFF  9102080    // 16384*12
#define WS_END    9298688

// ---------------------------------------------------------------------------
// Kernel 1: rotation matrices + translation + time embedding qemb = te@W_qt+b
// ---------------------------------------------------------------------------
__global__ __launch_bounds__(128) void prep_rt_qemb(
    const float* __restrict__ Ts, const float* __restrict__ timev,
    const float* __restrict__ W_qt, const float* __restrict__ b_qt,
    float* __restrict__ ws)
{
  int t = blockIdx.x, j = threadIdx.x;
  __shared__ float te[128];
  float tt = timev[t];
  int h = j & 63;
  float fr = __expf(-logf(10000.f) * (float)h / 63.f);
  float a = tt * fr;
  te[j] = (j < 64) ? sinf(a) : cosf(a);
  if (j == 0) {
    float qw = Ts[t*7+0], qx = Ts[t*7+1], qy = Ts[t*7+2], qz = Ts[t*7+3];
    float nrm = sqrtf(qw*qw + qx*qx + qy*qy + qz*qz);
    qw /= nrm; qx /= nrm; qy /= nrm; qz /= nrm;
    float* R = ws + R_OFF + t*9;
    R[0] = 1.f - 2.f*(qy*qy + qz*qz); R[1] = 2.f*(qx*qy - qw*qz); R[2] = 2.f*(qx*qz + qw*qy);
    R[3] = 2.f*(qx*qy + qw*qz); R[4] = 1.f - 2.f*(qx*qx + qz*qz); R[5] = 2.f*(qy*qz - qw*qx);
    R[6] = 2.f*(qx*qz - qw*qy); R[7] = 2.f*(qy*qz + qw*qx); R[8] = 1.f - 2.f*(qx*qx + qy*qy);
    ws[TR_OFF + t*3 + 0] = Ts[t*7+4];
    ws[TR_OFF + t*3 + 1] = Ts[t*7+5];
    ws[TR_OFF + t*3 + 2] = Ts[t*7+6];
  }
  __syncthreads();
  float acc = b_qt[j];
  for (int k = 0; k < 128; k++) acc += te[k] * W_qt[k*128 + j];
  ws[QE_OFF + t*128 + j] = acc;
}

// ---------------------------------------------------------------------------
// Kernel 2: G[s][t][o] = b1[s][o] + sum_k qemb[t][k] * W1[s][8+k][o]
// ---------------------------------------------------------------------------
__global__ __launch_bounds__(64) void prep_G(
    const float* __restrict__ W1_r, const float* __restrict__ b1_r,
    float* __restrict__ ws)
{
  int t = blockIdx.x, sidx = blockIdx.y, o = threadIdx.x;
  const float* W1 = W1_r + sidx*136*64;
  const float* qe = ws + QE_OFF + t*128;
  float acc = b1_r[sidx*64 + o];
  for (int k = 0; k < 128; k++) acc += qe[k] * W1[(8+k)*64 + o];
  ws[G_OFF + sidx*4096 + t*64 + o] = acc;
}

// ---------------------------------------------------------------------------
// Kernel 3: qx_flat (transformed query positions) + qf_t (transformed feats)
// ---------------------------------------------------------------------------
__global__ __launch_bounds__(256) void prep_Q(
    const float* __restrict__ query_x, const float* __restrict__ query_f,
    float* __restrict__ ws)
{
  int t = blockIdx.x, tid = threadIdx.x;
  __shared__ float Rs[9], tr[3];
  if (tid < 9) Rs[tid] = ws[R_OFF + t*9 + tid];
  if (tid < 3) tr[tid] = ws[TR_OFF + t*3 + tid];
  __syncthreads();
  for (int el = tid; el < 768; el += 256) {
    int q = el / 3, i = el - q*3;
    const float* x = query_x + q*3;
    ws[QX_OFF + t*768 + el] = Rs[i*3+0]*x[0] + Rs[i*3+1]*x[1] + Rs[i*3+2]*x[2] + tr[i];
  }
  for (int el = tid; el < 40960; el += 256) {
    int q = el / 160, j = el - q*160;
    float v;
    if (j < 64) {
      v = query_f[q*160 + j];
    } else {
      int c = (j - 64) / 3, i = (j - 64) - c*3;
      const float* qv = query_f + q*160 + 64 + c*3;
      v = Rs[i*3+0]*qv[0] + Rs[i*3+1]*qv[1] + Rs[i*3+2]*qv[2];
    }
    ws[QF_OFF + (size_t)t*40960 + el] = v;
  }
}

// ---------------------------------------------------------------------------
// Kernel 3b: W2T[s][o][k] = W2[s][k][o]  (contiguous weight rows per output)
// ---------------------------------------------------------------------------
__global__ __launch_bounds__(256) void prep_W2T(
    const float* __restrict__ W2_r, float* __restrict__ w2t)
{
  int sidx = blockIdx.x;
  const float* W2 = W2_r + sidx*64*192;
  float* T = w2t + sidx*12288;
  for (int idx = threadIdx.x; idx < 12288; idx += 256) {
    int o = idx >> 6, k = idx & 63;
    T[idx] = W2[k*192 + o];
  }
}

// ---------------------------------------------------------------------------
// Sort edges by dst: histogram -> exclusive scan -> scatter
// ---------------------------------------------------------------------------
__global__ __launch_bounds__(256) void hist_kernel(
    const int* __restrict__ ed0, const int* __restrict__ ed1,
    int* __restrict__ hist)
{
  int sc = blockIdx.y;
  const int* ed = sc ? ed1 : ed0;
  int e = blockIdx.x*256 + threadIdx.x;
  atomicAdd(hist + sc*NN + ed[e], 1);
}

__global__ __launch_bounds__(1024) void scan_kernel(
    const int* __restrict__ hist, int* __restrict__ start)
{
  int sc = blockIdx.x;
  const int* h = hist + sc*NN;
  int* st = start + sc*NN;
  __shared__ int lds[1024];
  int tid = threadIdx.x;
  int loc[16]; int s = 0;
  #pragma unroll
  for (int j = 0; j < 16; j++) { loc[j] = s; s += h[tid*16 + j]; }
  lds[tid] = s;
  __syncthreads();
  for (int off = 1; off < 1024; off <<= 1) {
    int v = lds[tid];
    int u = (tid >= off) ? lds[tid - off] : 0;
    __syncthreads();
    lds[tid] = v + u;
    __syncthreads();
  }
  int base = lds[tid] - s;   // exclusive across tiles
  #pragma unroll
  for (int j = 0; j < 16; j++) st[tid*16 + j] = base + loc[j];
}

__global__ __launch_bounds__(256) void scatter_kernel(
    const int* __restrict__ es0, const int* __restrict__ ed0,
    const int* __restrict__ es1, const int* __restrict__ ed1,
    const int* __restrict__ start, int* __restrict__ fill,
    int* __restrict__ ssrc, int* __restrict__ sdst)
{
  int sc = blockIdx.y;
  const int* es = sc ? es1 : es0;
  const int* ed = sc ? ed1 : ed0;
  int e = blockIdx.x*256 + threadIdx.x;
  int d = ed[e];
  int pos = start[sc*NN + d] + atomicAdd(fill + sc*NN + d, 1);
  ssrc[sc*EE + pos] = es[e];
  sdst[sc*EE + pos] = d;
}

// ---------------------------------------------------------------------------
// Kernel 4: per-edge MLP + message, sorted order, segmented wave reduction,
// head-lane atomics only (~5 per 64 edges per channel component)
// ---------------------------------------------------------------------------
#define SEGRED(v) { float _t; \
  _t = __shfl_down(v, 1);  v += mm0 ? _t : 0.f; \
  _t = __shfl_down(v, 2);  v += mm1 ? _t : 0.f; \
  _t = __shfl_down(v, 4);  v += mm2 ? _t : 0.f; \
  _t = __shfl_down(v, 8);  v += mm3 ? _t : 0.f; \
  _t = __shfl_down(v, 16); v += mm4 ? _t : 0.f; \
  _t = __shfl_down(v, 32); v += mm5 ? _t : 0.f; }

__global__ __launch_bounds__(256) void edge_kernel(
    const float* __restrict__ key_x, const float* __restrict__ key_f,
    const int* __restrict__ ssrc, const int* __restrict__ sdst,
    const float* __restrict__ W1, const float* __restrict__ W2T,
    const float* __restrict__ b2, const float* __restrict__ Gtab,
    const float* __restrict__ qx_flat, float* __restrict__ numbuf)
{
  __shared__ float Gs[64*65];   // stride 65: random-t gathers spread banks
  for (int idx = threadIdx.x; idx < 4096; idx += 256)
    Gs[(idx >> 6)*65 + (idx & 63)] = Gtab[idx];
  __syncthreads();

  int p = blockIdx.x*256 + threadIdx.x;
  int lane = threadIdx.x & 63;
  int s = ssrc[p], d = sdst[p];

  const float* qx = qx_flat + d*3;
  float rel0 = key_x[s*3+0] - qx[0];
  float rel1 = key_x[s*3+1] - qx[1];
  float rel2 = key_x[s*3+2] - qx[2];
  float r = sqrtf(rel0*rel0 + rel1*rel1 + rel2*rel2);
  float rinv = 1.f / (r + 1e-8f);
  float dir0 = rel0*rinv, dir1 = rel1*rinv, dir2 = rel2*rinv;
  float rb[8];
  #pragma unroll
  for (int j = 0; j < 8; j++) {
    float dd = r - (float)j * (4.f/7.f);
    rb[j] = __expf(-4.f * dd * dd);
  }
  int t = d >> 8;
  const float* grow = Gs + t*65;

  // layer1 (rb part; qemb part prefolded into G)
  float h1[64];
  #pragma unroll
  for (int kk = 0; kk < 64; kk++) {
    float a = grow[kk];
    #pragma unroll
    for (int j = 0; j < 8; j++) a += rb[j] * W1[j*64 + kk];
    h1[kk] = a / (1.f + __expf(-a));   // silu
  }

  // segmentation masks (dst non-decreasing within wave)
  int dn;
  dn = __shfl_down(d, 1);  bool mm0 = (lane + 1  < 64) && (dn == d);
  dn = __shfl_down(d, 2);  bool mm1 = (lane + 2  < 64) && (dn == d);
  dn = __shfl_down(d, 4);  bool mm2 = (lane + 4  < 64) && (dn == d);
  dn = __shfl_down(d, 8);  bool mm3 = (lane + 8  < 64) && (dn == d);
  dn = __shfl_down(d, 16); bool mm4 = (lane + 16 < 64) && (dn == d);
  dn = __shfl_down(d, 32); bool mm5 = (lane + 32 < 64) && (dn == d);
  int dp = __shfl_up(d, 1);
  bool head = (lane == 0) || (dp != d);

  const float* kf = key_f + (size_t)s * 160;
  float* nrow = numbuf + (size_t)d * 160;

  #pragma unroll 1
  for (int c = 0; c < 32; c++) {
    float ks = kf[c];
    float k0 = kf[64+3*c+0], k1 = kf[64+3*c+1], k2 = kf[64+3*c+2];
    const float* w0 = W2T + (size_t)c*64;
    const float* w1 = W2T + (size_t)(64+c)*64;
    const float* w2 = W2T + (size_t)(96+c)*64;
    const float* w3 = W2T + (size_t)(128+c)*64;
    const float* w4 = W2T + (size_t)(160+c)*64;
    float a0 = b2[c], a1 = b2[64+c], a2 = b2[96+c], a3 = b2[128+c], a4 = b2[160+c];
    #pragma unroll
    for (int k = 0; k < 64; k++) {
      float hk = h1[k];
      a0 += hk*w0[k]; a1 += hk*w1[k]; a2 += hk*w2[k]; a3 += hk*w3[k]; a4 += hk*w4[k];
    }
    float dt = k0*dir0 + k1*dir1 + k2*dir2;
    float ms = a0*ks + a3*dt;
    float cr0 = k1*dir2 - k2*dir1;
    float cr1 = k2*dir0 - k0*dir2;
    float cr2 = k0*dir1 - k1*dir0;
    float sv = a2*ks;
    float m0 = a1*k0 + sv*dir0 + a4*cr0;
    float m1 = a1*k1 + sv*dir1 + a4*cr1;
    float m2 = a1*k2 + sv*dir2 + a4*cr2;
    SEGRED(ms); SEGRED(m0); SEGRED(m1); SEGRED(m2);
    if (head) {
      atomicAdd(nrow + c, ms);
      atomicAdd(nrow + 64 + 3*c + 0, m0);
      atomicAdd(nrow + 64 + 3*c + 1, m1);
      atomicAdd(nrow + 64 + 3*c + 2, m2);
    }
  }
  #pragma unroll 2
  for (int c = 32; c < 64; c++) {
    float ks = kf[c];
    const float* w0 = W2T + (size_t)c*64;
    float a0 = b2[c];
    #pragma unroll
    for (int k = 0; k < 64; k++) a0 += h1[k]*w0[k];
    float ms = a0*ks;
    SEGRED(ms);
    if (head) atomicAdd(nrow + c, ms);
  }
}

// ---------------------------------------------------------------------------
// Kernel 5: tp_head, writes per-node partials (no atomics)
// ---------------------------------------------------------------------------
__global__ __launch_bounds__(64) void head_kernel(
    const float* __restrict__ num0, const float* __restrict__ num1,
    const int* __restrict__ h0, const int* __restrict__ h1c,
    const float* __restrict__ qf_t, const float* __restrict__ Rtab,
    const float* __restrict__ query_x, const float* __restrict__ query_w,
    const float* __restrict__ p00, const float* __restrict__ prest,
    const float* __restrict__ Ws_tp, const float* __restrict__ Wv_tp,
    float* __restrict__ part)
{
  int n = blockIdx.x;
  int lane = threadIdx.x;
  int t = n >> 8, q = n & 255;
  __shared__ float sb[96];
  __shared__ float vb[96][3];
  const float* n0 = num0 + (size_t)n*160;
  const float* n1 = num1 + (size_t)n*160;
  const float* qf = qf_t + (size_t)n*160;
  float ic0 = 1.f / ((float)h0[n] + 1e-8f);
  float ic1 = 1.f / ((float)h1c[n] + 1e-8f);
  int c = lane;
  if (c < 64) sb[c] = (n0[c]*ic0 + n1[c]*ic1) * qf[c];
  if (c < 32) {
    float ks = n0[c]*ic0 + n1[c]*ic1;
    float qs = qf[c];
    float k0 = n0[64+3*c+0]*ic0 + n1[64+3*c+0]*ic1;
    float k1 = n0[64+3*c+1]*ic0 + n1[64+3*c+1]*ic1;
    float k2 = n0[64+3*c+2]*ic0 + n1[64+3*c+2]*ic1;
    float q0 = qf[64+3*c+0], q1 = qf[64+3*c+1], q2 = qf[64+3*c+2];
    sb[64+c] = k0*q0 + k1*q1 + k2*q2;
    vb[c][0] = k0*qs;  vb[c][1] = k1*qs;  vb[c][2] = k2*qs;
    vb[32+c][0] = ks*q0;  vb[32+c][1] = ks*q1;  vb[32+c][2] = ks*q2;
    vb[64+c][0] = k1*q2 - k2*q1;
    vb[64+c][1] = k2*q0 - k0*q2;
    vb[64+c][2] = k0*q1 - k1*q0;
  }
  __syncthreads();

  int i = lane >> 5, o = lane & 31;
  const float* Ws = Ws_tp + i*96*33;
  const float* Wv = Wv_tp + i*96*32;
  const float* pp = p00 + i*64;
  const float* pr = prest + i*128;
  float g = 0.f, v0 = 0.f, v1 = 0.f, v2 = 0.f;
  for (int c2 = 0; c2 < 96; c2++) {
    float ps = (c2 < 64) ? pp[c2] : pr[c2];        // p00[i][c] / prest[i][2][c-64]
    float pv = (c2 < 64) ? pr[c2] : pr[c2 + 32];   // prest[i][0/1/3][...]
    g += sb[c2] * ps * Ws[c2*33 + o + 1];
    float pw = pv * Wv[c2*32 + o];
    v0 += vb[c2][0] * pw;
    v1 += vb[c2][1] * pw;
    v2 += vb[c2][2] * pw;
  }
  g = 1.f / (1.f + __expf(-g));
  v0 *= g; v1 *= g; v2 *= g;
  #pragma unroll
  for (int m = 16; m >= 1; m >>= 1) {
    v0 += __shfl_xor(v0, m, 32);
    v1 += __shfl_xor(v1, m, 32);
    v2 += __shfl_xor(v2, m, 32);
  }
  if (o == 0) {
    v0 *= (1.f/32.f); v1 *= (1.f/32.f); v2 *= (1.f/32.f);
    const float* R = Rtab + t*9;
    float r0 = R[0]*v0 + R[3]*v1 + R[6]*v2;
    float r1 = R[1]*v0 + R[4]*v1 + R[7]*v2;
    float r2 = R[2]*v0 + R[5]*v1 + R[8]*v2;
    float w = query_w[q];
    float* pout = part + (size_t)n*12;
    if (i == 0) {
      pout[0] = w*r0; pout[1] = w*r1; pout[2] = w*r2;      // lin
      float x0 = query_x[q*3+0], x1 = query_x[q*3+1], x2 = query_x[q*3+2];
      pout[3] = w*(x1*r2 - x2*r1);                          // orb -> ang
      pout[4] = w*(x2*r0 - x0*r2);
      pout[5] = w*(x0*r1 - x1*r0);
    } else {
      pout[6] = w*r0; pout[7] = w*r1; pout[8] = w*r2;      // ang
    }
  }
}

// ---------------------------------------------------------------------------
// Kernel 6: reduce partials over q (256 per template)
// ---------------------------------------------------------------------------
__global__ __launch_bounds__(256) void final_kernel(
    const float* __restrict__ part, float* __restrict__ out)
{
  int t = blockIdx.x, q = threadIdx.x;
  const float* pr = part + ((size_t)(t*256 + q))*12;
  float v[9];
  #pragma unroll
  for (int i = 0; i < 9; i++) v[i] = pr[i];
  #pragma unroll
  for (int m = 32; m >= 1; m >>= 1) {
    #pragma unroll
    for (int i = 0; i < 9; i++) v[i] += __shfl_down(v[i], m);
  }
  __shared__ float lds[4][9];
  int w = q >> 6, l = q & 63;
  if (l == 0) {
    #pragma unroll
    for (int i = 0; i < 9; i++) lds[w][i] = v[i];
  }
  __syncthreads();
  if (q == 0) {
    float o[9];
    #pragma unroll
    for (int i = 0; i < 9; i++) o[i] = lds[0][i] + lds[1][i] + lds[2][i] + lds[3][i];
    out[t*3+0] = o[3] + o[6];        // ang_vel = orb + ang
    out[t*3+1] = o[4] + o[7];
    out[t*3+2] = o[5] + o[8];
    out[192 + t*3+0] = o[0];         // lin_vel
    out[192 + t*3+1] = o[1];
    out[192 + t*3+2] = o[2];
  }
}

// ---------------------------------------------------------------------------
extern "C" void kernel_launch(void* const* d_in, const int* in_sizes, int n_in,
                              void* d_out, int out_size, void* d_ws, size_t ws_size,
                              hipStream_t stream)
{
  const float* Ts      = (const float*)d_in[0];
  const float* timev   = (const float*)d_in[1];
  const float* query_x = (const float*)d_in[2];
  const float* query_f = (const float*)d_in[3];
  const float* query_w = (const float*)d_in[4];
  const float* key_x_0 = (const float*)d_in[5];
  const float* key_f_0 = (const float*)d_in[6];
  const float* key_x_1 = (const float*)d_in[7];
  const float* key_f_1 = (const float*)d_in[8];
  const int*   es0     = (const int*)d_in[9];
  const int*   ed0     = (const int*)d_in[10];
  const int*   es1     = (const int*)d_in[11];
  const int*   ed1     = (const int*)d_in[12];
  const float* W_qt    = (const float*)d_in[13];
  const float* b_qt    = (const float*)d_in[14];
  const float* W1_r    = (const float*)d_in[15];
  const float* b1_r    = (const float*)d_in[16];
  const float* W2_r    = (const float*)d_in[17];
  const float* b2_r    = (const float*)d_in[18];
  const float* p00     = (const float*)d_in[19];
  const float* prest   = (const float*)d_in[20];
  const float* Ws_tp   = (const float*)d_in[21];
  const float* Wv_tp   = (const float*)d_in[22];
  float* ws  = (float*)d_ws;
  float* out = (float*)d_out;

  int* histp  = (int*)(ws + HIST_OFF);
  int* startp = (int*)(ws + START_OFF);
  int* fillp  = (int*)(ws + FILL_OFF);
  int* ssrcp  = (int*)(ws + SSRC_OFF);
  int* sdstp  = (int*)(ws + SDST_OFF);

  // zero: num accumulators + hist/start/fill
  hipMemsetAsync(ws + N0_OFF, 0, (size_t)(2*NN*160) * sizeof(float), stream);
  hipMemsetAsync(ws + HIST_OFF, 0, (size_t)(6*NN) * sizeof(float), stream);

  prep_rt_qemb<<<64, 128, 0, stream>>>(Ts, timev, W_qt, b_qt, ws);
  prep_G<<<dim3(64, 2), 64, 0, stream>>>(W1_r, b1_r, ws);
  prep_Q<<<64, 256, 0, stream>>>(query_x, query_f, ws);
  prep_W2T<<<2, 256, 0, stream>>>(W2_r, ws + W2T_OFF);

  hist_kernel<<<dim3(1024, 2), 256, 0, stream>>>(ed0, ed1, histp);
  scan_kernel<<<2, 1024, 0, stream>>>(histp, startp);
  scatter_kernel<<<dim3(1024, 2), 256, 0, stream>>>(
      es0, ed0, es1, ed1, startp, fillp, ssrcp, sdstp);

  edge_kernel<<<1024, 256, 0, stream>>>(
      key_x_0, key_f_0, ssrcp, sdstp,
      W1_r, ws + W2T_OFF, b2_r,
      ws + G_OFF, ws + QX_OFF, ws + N0_OFF);
  edge_kernel<<<1024, 256, 0, stream>>>(
      key_x_1, key_f_1, ssrcp + EE, sdstp + EE,
      W1_r + 136*64, ws + W2T_OFF + 12288, b2_r + 192,
      ws + G_OFF + 4096, ws + QX_OFF, ws + N1_OFF);

  head_kernel<<<16384, 64, 0, stream>>>(
      ws + N0_OFF, ws + N1_OFF, histp, histp + NN,
      ws + QF_OFF, ws + R_OFF,
      query_x, query_w, p00, prest, Ws_tp, Wv_tp, ws + PART_OFF);

  final_kernel<<<64, 256, 0, stream>>>(ws + PART_OFF, out);
}